// Round 1
// baseline (148.978 us; speedup 1.0000x reference)
//
#include <hip/hip_runtime.h>
#include <hip/hip_bf16.h>

#define VOCAB 512
#define W 20

// One wave (64 lanes) per output row of 512 floats.
// Block = 256 threads = 4 waves = 4 rows; 8 KB LDS.
__global__ __launch_bounds__(256) void fofe_kernel(
    const int*   __restrict__ sents,    // [rows * W]
    const int*   __restrict__ lengths,  // [B]
    const float* __restrict__ alpha_p,  // [1]
    float*       __restrict__ out,      // [rows * VOCAB + B]
    int rows, int B)
{
    __shared__ float lds[4 * VOCAB];

    const int tid  = threadIdx.x;
    const int wave = tid >> 6;
    const int lane = tid & 63;
    const int row  = blockIdx.x * 4 + wave;

    float*  lrow  = &lds[wave * VOCAB];
    float4* lrow4 = (float4*)lrow;

    // --- zero this wave's LDS row: 8 floats (2 x float4) per lane ---
    const float4 z = make_float4(0.f, 0.f, 0.f, 0.f);
    lrow4[lane * 2 + 0] = z;
    lrow4[lane * 2 + 1] = z;

    __syncthreads();

    // --- scatter the 20 decay weights: w[k] = alpha^(W-1-k) ---
    if (row < rows && lane < W) {
        const float alpha = alpha_p[0];
        const int   c     = sents[row * W + lane];
        const float w     = powf(alpha, (float)(W - 1 - lane));  // k=W-1 -> alpha^0 = 1
        atomicAdd(&lrow[c], w);  // ds_add_f32; handles duplicate chars in a row
    }

    __syncthreads();

    // --- coalesced write-out: 2 x global_store_dwordx4 per lane ---
    if (row < rows) {
        float4* orow4 = (float4*)(out + (size_t)row * VOCAB);
        orow4[lane * 2 + 0] = lrow4[lane * 2 + 0];
        orow4[lane * 2 + 1] = lrow4[lane * 2 + 1];
    }

    // --- output 1: lengths pass-through, written as float values at the tail ---
    if (blockIdx.x == 0) {
        const size_t base = (size_t)rows * VOCAB;
        for (int i = tid; i < B; i += blockDim.x) {
            out[base + i] = (float)lengths[i];
        }
    }
}

extern "C" void kernel_launch(void* const* d_in, const int* in_sizes, int n_in,
                              void* d_out, int out_size, void* d_ws, size_t ws_size,
                              hipStream_t stream) {
    const int*   sents   = (const int*)d_in[0];    // [B*S*W] int32
    const int*   lengths = (const int*)d_in[1];    // [B] int32
    const float* alpha   = (const float*)d_in[2];  // [1] float32
    float*       out     = (float*)d_out;

    const int rows = in_sizes[0] / W;   // B*S = 65536
    const int B    = in_sizes[1];       // 256

    const int blocks = (rows + 3) / 4;  // 4 rows per block (one per wave)
    fofe_kernel<<<blocks, 256, 0, stream>>>(sents, lengths, alpha, out, rows, B);
}

// Round 3
// 145.916 us; speedup vs baseline: 1.0210x; 1.0210x over previous
//
#include <hip/hip_runtime.h>
#include <hip/hip_bf16.h>

#define VOCAB 512
#define W 20

typedef float f4 __attribute__((ext_vector_type(4)));

// One wave = one block = one output row of 512 floats. 2 KB LDS per block.
// 65536 blocks; barriers are wave-local (single-wave workgroup) so waves
// are fully decoupled from each other's memory latency.
__global__ __launch_bounds__(64) void fofe_kernel(
    const int*   __restrict__ sents,    // [rows * W]
    const int*   __restrict__ lengths,  // [B]
    const float* __restrict__ alpha_p,  // [1]
    float*       __restrict__ out,      // [rows * VOCAB + B]
    int rows, int B)
{
    __shared__ float lrow[VOCAB];

    const int lane = threadIdx.x;   // 0..63
    const int row  = blockIdx.x;

    f4* lrow4 = (f4*)lrow;

    // --- zero the LDS row: 2 x float4 per lane, contiguous per instruction ---
    const f4 z = (f4){0.f, 0.f, 0.f, 0.f};
    lrow4[lane]      = z;
    lrow4[lane + 64] = z;

    __syncthreads();  // single-wave workgroup: near-free

    // --- scatter the 20 decay weights: w[k] = alpha^(W-1-k) ---
    if (lane < W) {
        const float alpha = alpha_p[0];
        const int   c     = sents[row * W + lane];
        const float e     = (float)(W - 1 - lane);
        // v_log_f32 + v_mul + v_exp_f32 (plus small fixup) instead of OCML powf.
        float w = exp2f(log2f(alpha) * e);
        if (lane == W - 1) w = 1.0f;   // alpha^0 == 1 exactly; also dodges -inf*0 if alpha==0
        atomicAdd(&lrow[c], w);        // ds_add_f32; handles duplicate chars
    }

    __syncthreads();

    // --- coalesced streaming write-out: 2 x global_store_dwordx4 per lane,
    //     each instruction covers a contiguous 1 KB span ---
    f4* orow4 = (f4*)(out + (size_t)row * VOCAB);
    __builtin_nontemporal_store(lrow4[lane],      &orow4[lane]);
    __builtin_nontemporal_store(lrow4[lane + 64], &orow4[lane + 64]);

    // --- output 1: lengths pass-through as float values at the tail ---
    if (row == 0) {
        const size_t base = (size_t)rows * VOCAB;
        for (int i = lane; i < B; i += 64) {
            out[base + i] = (float)lengths[i];
        }
    }
}

extern "C" void kernel_launch(void* const* d_in, const int* in_sizes, int n_in,
                              void* d_out, int out_size, void* d_ws, size_t ws_size,
                              hipStream_t stream) {
    const int*   sents   = (const int*)d_in[0];    // [B*S*W] int32
    const int*   lengths = (const int*)d_in[1];    // [B] int32
    const float* alpha   = (const float*)d_in[2];  // [1] float32
    float*       out     = (float*)d_out;

    const int rows = in_sizes[0] / W;   // B*S = 65536
    const int B    = in_sizes[1];       // 256

    fofe_kernel<<<rows, 64, 0, stream>>>(sents, lengths, alpha, out, rows, B);
}

// Round 4
// 144.555 us; speedup vs baseline: 1.0306x; 1.0094x over previous
//
#include <hip/hip_runtime.h>
#include <hip/hip_bf16.h>

#define VOCAB 512
#define W 20
#define R 8   // rows per block

typedef float f4 __attribute__((ext_vector_type(4)));

// 256-thread block builds R=8 consecutive rows in 16 KB LDS, then streams
// them out as one contiguous 16 KB write (4 x dwordx4 per thread).
__global__ __launch_bounds__(256) void fofe_kernel(
    const int*   __restrict__ sents,    // [rows * W]
    const int*   __restrict__ lengths,  // [B]
    const float* __restrict__ alpha_p,  // [1]
    float*       __restrict__ out,      // [rows * VOCAB + B]
    int rows, int B)
{
    __shared__ float lds[R * VOCAB];    // 16 KB

    const int tid  = threadIdx.x;
    const int row0 = blockIdx.x * R;

    // --- issue the char loads FIRST (long-latency), overlap with LDS zeroing ---
    float w = 0.f;
    int   c = 0;
    int   r = 0;
    if (tid < R * W) {
        r = tid / W;                       // row within block
        const int k = tid - r * W;         // char position
        c = sents[(size_t)(row0 + r) * W + k];   // coalesced 640 B block load
        const float alpha = alpha_p[0];
        w = exp2f(log2f(alpha) * (float)(W - 1 - k));
        if (k == W - 1) w = 1.0f;          // alpha^0 == 1; dodges -inf*0 at alpha==0
    }

    // --- zero 16 KB LDS: 4 x f4 per thread ---
    f4* l4 = (f4*)lds;
    #pragma unroll
    for (int i = 0; i < 4; ++i)
        l4[tid + 256 * i] = (f4){0.f, 0.f, 0.f, 0.f};

    __syncthreads();

    // --- scatter decay weights (ds_add_f32 handles duplicate chars) ---
    if (tid < R * W)
        atomicAdd(&lds[r * VOCAB + c], w);

    __syncthreads();

    // --- contiguous 16 KB streaming write-out: 4 x global_store_dwordx4 ---
    f4* o4 = (f4*)(out + (size_t)row0 * VOCAB);
    #pragma unroll
    for (int i = 0; i < 4; ++i)
        __builtin_nontemporal_store(l4[tid + 256 * i], &o4[tid + 256 * i]);

    // --- output 1: lengths pass-through as float values at the tail ---
    if (blockIdx.x == 0 && tid < B) {
        out[(size_t)rows * VOCAB + tid] = (float)lengths[tid];
    }
}

extern "C" void kernel_launch(void* const* d_in, const int* in_sizes, int n_in,
                              void* d_out, int out_size, void* d_ws, size_t ws_size,
                              hipStream_t stream) {
    const int*   sents   = (const int*)d_in[0];    // [B*S*W] int32
    const int*   lengths = (const int*)d_in[1];    // [B] int32
    const float* alpha   = (const float*)d_in[2];  // [1] float32
    float*       out     = (float*)d_out;

    const int rows = in_sizes[0] / W;   // B*S = 65536
    const int B    = in_sizes[1];       // 256

    const int blocks = (rows + R - 1) / R;   // 8192
    fofe_kernel<<<blocks, 256, 0, stream>>>(sents, lengths, alpha, out, rows, B);
}